// Round 7
// baseline (25.302 us; speedup 1.0000x reference)
//
#include <hip/hip_runtime.h>

// out[o] = sum_t d1[t + o - 301] * d2[t],  o in [0,603), t in [0,3000)
// Parity-split GEMM per channel (R4 structure + B LDS XOR-swizzle):
//   o = 2*(16a + m) + par,  C_par[m,a] = sum_s d1[s + 2m + par - 301] * d2[s - 32a]
// One wave per channel (BLOCK=64, grid=2048): staging STREAMED through the
// k-loop in 6 chunks of 16 k-steps. B-fragment FIFO (tile1 = tile0 @ i-16).
//
// R7 fix: B's ds_read_b128 lanes stride -64B = 8-way bank conflict (only two
// 16B bank-groups touched). XOR-swizzle B at 16B-unit granularity:
//   swz(d) = d ^ (((d>>5)&7)<<2)      (d = dword index, 16B-aligned accesses)
// -> each bank-group hit exactly 2x per 16 lanes (free). Applied to ALL B
// accesses (zero, stage, FIFO prefill, main read). A stays linear (audited
// conflict-free: lane addresses 2+4q+r span distinct banks).

#define NT    3000
#define NOUT  603
#define BLOCK 64
#define L1DW  1696
#define L2DW  2048

typedef short bf16x8 __attribute__((ext_vector_type(8)));
typedef float f32x4  __attribute__((ext_vector_type(4)));

static __device__ __forceinline__ uint f2bf(float f) {
    union { float f; uint u; } a; a.f = f;            // RNE f32 -> bf16
    return (a.u + 0x7fffu + ((a.u >> 16) & 1u)) >> 16;
}

static __device__ __forceinline__ int swz(int d) {    // B-layout unit swizzle
    return d ^ (((d >> 5) & 7) << 2);
}

__global__ __launch_bounds__(BLOCK, 2) void xcorr_mfma(
    const float* __restrict__ d1g, const float* __restrict__ d2g,
    float* __restrict__ out)
{
    __shared__ __align__(16) uint l1[L1DW];
    __shared__ __align__(16) uint l2[L2DW];

    const int lane = threadIdx.x & 63;
    const int q = lane >> 4, r = lane & 15;
    const int ch = blockIdx.x;
    const float* __restrict__ g1 = d1g + (size_t)ch * NT;
    const float* __restrict__ g2 = d2g + (size_t)ch * NT;

    // --- Zero pad regions (same-wave LDS ordering is program order).
    for (int j = lane; j < 196; j += BLOCK) {
        const int dw = (j < 152) ? j : 1652 + (j - 152);
        l1[dw] = 0u;
    }
    for (int j = lane; j < 548; j += BLOCK) {
        const int dw = (j < 384) ? j : 1884 + (j - 384);
        l2[swz(dw)] = 0u;                       // swizzled B layout
    }

    // --- 256-dword staging: lane handles dwords [dstart+4*lane, +4).
    auto stageA = [&](int dstart) {
        const int d = dstart + 4 * lane;
        const int e0 = 2 * (d - 152);
        if (e0 < NT) {
            const float4 v = *(const float4*)(g1 + e0);
            const float4 w = *(const float4*)(g1 + e0 + 4);
            int4 p;
            p.x = (int)(f2bf(v.x) | (f2bf(v.y) << 16));
            p.y = (int)(f2bf(v.z) | (f2bf(v.w) << 16));
            p.z = (int)(f2bf(w.x) | (f2bf(w.y) << 16));
            p.w = (int)(f2bf(w.z) | (f2bf(w.w) << 16));
            *(int4*)(l1 + d) = p;
        }
    };
    auto stageB = [&](int dstart) {
        const int d = dstart + 4 * lane;
        const int e0 = 2 * (d - 384);
        if (e0 < NT) {
            const float4 v = *(const float4*)(g2 + e0);
            const float4 w = *(const float4*)(g2 + e0 + 4);
            int4 p;
            p.x = (int)(f2bf(v.x) | (f2bf(v.y) << 16));
            p.y = (int)(f2bf(v.z) | (f2bf(v.w) << 16));
            p.z = (int)(f2bf(w.x) | (f2bf(w.y) << 16));
            p.w = (int)(f2bf(w.z) | (f2bf(w.w) << 16));
            *(int4*)(l2 + swz(d)) = p;          // swizzled B layout
        }
    };

    // --- Prologue: A dwords [152,664), B dwords [384,896).
    stageA(152); stageA(408);
    stageB(384); stageB(640);

    // --- B FIFO prefill: slot s <- tile0 frag of step s-16 (reads [16,512)).
    int4 fifo[16];
    {
        const int dbP = 256 + 4 * q - 16 * r;
        #pragma unroll
        for (int s = 0; s < 16; ++s)
            fifo[s] = *(const int4*)(l2 + swz(dbP + 16 * s));
    }

    f32x4 a00 = {0.f,0.f,0.f,0.f};   // aPT: P = parity, T = n-tile
    f32x4 a10 = {0.f,0.f,0.f,0.f};
    f32x4 a01 = {0.f,0.f,0.f,0.f};
    f32x4 a11 = {0.f,0.f,0.f,0.f};

    int da = 130 + 4 * q + r;        // A dword base (+16/step)
    int db = 512 + 4 * q - 16 * r;   // tile0 B dword base (+16/step)
    int aPre = 664, bPre = 896;      // staged frontiers

    for (int c = 0; c < 6; ++c) {
        // Prefetch loads for future chunks (issued before the MFMA steps).
        const int dA = aPre + 4 * lane, eA = 2 * (dA - 152);
        const int dB = bPre + 4 * lane, eB = 2 * (dB - 384);
        const bool okA = eA < NT, okB = eB < NT;
        float4 va0, va1, vb0, vb1;
        if (okA) { va0 = *(const float4*)(g1 + eA); va1 = *(const float4*)(g1 + eA + 4); }
        if (okB) { vb0 = *(const float4*)(g2 + eB); vb1 = *(const float4*)(g2 + eB + 4); }

        #pragma unroll
        for (int u = 0; u < 16; ++u) {
            const uint* pa = (const uint*)l1 + da;
            const uint Dm1 = pa[-1], D0 = pa[0], D1 = pa[1], D2 = pa[2], D3 = pa[3];

            union { uint w[4]; bf16x8 v; int4 i4; } f1, f0, g0, g1u;
            f1.w[0] = D0; f1.w[1] = D1; f1.w[2] = D2; f1.w[3] = D3;   // par=1
            f0.w[0] = (Dm1 >> 16) | (D0 << 16);                       // par=0
            f0.w[1] = (D0  >> 16) | (D1 << 16);
            f0.w[2] = (D1  >> 16) | (D2 << 16);
            f0.w[3] = (D2  >> 16) | (D3 << 16);

            g0.i4 = *(const int4*)((const uint*)l2 + swz(db));  // tile0 (step i)
            g1u.i4 = fifo[u];                                   // tile1 (@ i-16)
            fifo[u] = g0.i4;

            a00 = __builtin_amdgcn_mfma_f32_16x16x32_bf16(f0.v, g0.v,  a00, 0, 0, 0);
            a10 = __builtin_amdgcn_mfma_f32_16x16x32_bf16(f1.v, g0.v,  a10, 0, 0, 0);
            a01 = __builtin_amdgcn_mfma_f32_16x16x32_bf16(f0.v, g1u.v, a01, 0, 0, 0);
            a11 = __builtin_amdgcn_mfma_f32_16x16x32_bf16(f1.v, g1u.v, a11, 0, 0, 0);

            da += 16; db += 16;
        }

        // Convert + LDS write (read by chunk c+1/c+2 -> a chunk of slack).
        if (okA) {
            int4 p;
            p.x = (int)(f2bf(va0.x) | (f2bf(va0.y) << 16));
            p.y = (int)(f2bf(va0.z) | (f2bf(va0.w) << 16));
            p.z = (int)(f2bf(va1.x) | (f2bf(va1.y) << 16));
            p.w = (int)(f2bf(va1.z) | (f2bf(va1.w) << 16));
            *(int4*)(l1 + dA) = p;
        }
        if (okB) {
            int4 p;
            p.x = (int)(f2bf(vb0.x) | (f2bf(vb0.y) << 16));
            p.y = (int)(f2bf(vb0.z) | (f2bf(vb0.w) << 16));
            p.z = (int)(f2bf(vb1.x) | (f2bf(vb1.y) << 16));
            p.w = (int)(f2bf(vb1.z) | (f2bf(vb1.w) << 16));
            *(int4*)(l2 + swz(dB)) = p;         // swizzled B layout
        }
        aPre += 256; bPre += 256;
    }

    // --- Store: lane (q,r), reg rr, parity p -> o = 512*tile + 32r + 8q + 2rr + p.
    float* o = out + (size_t)ch * NOUT;
    {
        const int X = 32 * r + 8 * q;            // tile0: X+7 <= 511 < 603
        float4 s0 = {a00[0], a10[0], a00[1], a10[1]};
        float4 s1 = {a00[2], a10[2], a00[3], a10[3]};
        *(float4*)(o + X)     = s0;
        *(float4*)(o + X + 4) = s1;
    }
    {
        const int X = 512 + 32 * r + 8 * q;
        if (X + 7 < NOUT) {
            float4 s0 = {a01[0], a11[0], a01[1], a11[1]};
            float4 s1 = {a01[2], a11[2], a01[3], a11[3]};
            *(float4*)(o + X)     = s0;
            *(float4*)(o + X + 4) = s1;
        } else if (X < NOUT) {
            const float v[8] = {a01[0], a11[0], a01[1], a11[1],
                                a01[2], a11[2], a01[3], a11[3]};
            #pragma unroll
            for (int e = 0; e < 8; ++e)
                if (X + e < NOUT) o[X + e] = v[e];
        }
    }
}

extern "C" void kernel_launch(void* const* d_in, const int* in_sizes, int n_in,
                              void* d_out, int out_size, void* d_ws, size_t ws_size,
                              hipStream_t stream) {
    const float* d1 = (const float*)d_in[0];
    const float* d2 = (const float*)d_in[1];
    float* out = (float*)d_out;
    const int nChannels = in_sizes[0] / NT;     // 2048
    xcorr_mfma<<<nChannels, BLOCK, 0, stream>>>(d1, d2, out);
}

// Round 8
// 21.891 us; speedup vs baseline: 1.1558x; 1.1558x over previous
//
#include <hip/hip_runtime.h>

// out[o] = sum_t d1[t + o - 301] * d2[t],  o in [0,603), t in [0,3000)
// Parity-split GEMM per channel (R4 structure + explicit 1-deep SW pipeline):
//   o = 2*(16a + m) + par,  C_par[m,a] = sum_s d1[s + 2m + par - 301] * d2[s - 32a]
// One wave per channel (BLOCK=64, grid=2048): staging STREAMED through the
// k-loop in 6 chunks of 16 k-steps. B-fragment FIFO (tile1 = tile0 @ i-16).
//
// R8: software-pipeline the inner loop — prefetch step u+1's LDS data (5 A
// dwords + 1 B b128) into registers BEFORE step u's MFMAs, so ds_read latency
// (~64-120 cyc) hides under the ~80 cyc of MFMA+VALU per step. Cross-chunk
// prefetch is safe (reads trail the chunk's stage-writes by >150 dwords);
// the very last step's prefetch is skipped (LDS OOB guard).

#define NT    3000
#define NOUT  603
#define BLOCK 64
#define L1DW  1696
#define L2DW  2048

typedef short bf16x8 __attribute__((ext_vector_type(8)));
typedef float f32x4  __attribute__((ext_vector_type(4)));

static __device__ __forceinline__ uint f2bf(float f) {
    union { float f; uint u; } a; a.f = f;            // RNE f32 -> bf16
    return (a.u + 0x7fffu + ((a.u >> 16) & 1u)) >> 16;
}

struct AFrag { uint m1, d0, d1, d2, d3; };            // A dwords da-1..da+3

__global__ __launch_bounds__(BLOCK, 2) void xcorr_mfma(
    const float* __restrict__ d1g, const float* __restrict__ d2g,
    float* __restrict__ out)
{
    __shared__ __align__(16) uint l1[L1DW];
    __shared__ __align__(16) uint l2[L2DW];

    const int lane = threadIdx.x & 63;
    const int q = lane >> 4, r = lane & 15;
    const int ch = blockIdx.x;
    const float* __restrict__ g1 = d1g + (size_t)ch * NT;
    const float* __restrict__ g2 = d2g + (size_t)ch * NT;

    // --- Zero pad regions (same-wave LDS ordering is program order).
    for (int j = lane; j < 196; j += BLOCK) {
        const int dw = (j < 152) ? j : 1652 + (j - 152);
        l1[dw] = 0u;
    }
    for (int j = lane; j < 548; j += BLOCK) {
        const int dw = (j < 384) ? j : 1884 + (j - 384);
        l2[dw] = 0u;
    }

    // --- 256-dword staging: lane handles dwords [dstart+4*lane, +4).
    auto stageA = [&](int dstart) {
        const int d = dstart + 4 * lane;
        const int e0 = 2 * (d - 152);
        if (e0 < NT) {
            const float4 v = *(const float4*)(g1 + e0);
            const float4 w = *(const float4*)(g1 + e0 + 4);
            int4 p;
            p.x = (int)(f2bf(v.x) | (f2bf(v.y) << 16));
            p.y = (int)(f2bf(v.z) | (f2bf(v.w) << 16));
            p.z = (int)(f2bf(w.x) | (f2bf(w.y) << 16));
            p.w = (int)(f2bf(w.z) | (f2bf(w.w) << 16));
            *(int4*)(l1 + d) = p;
        }
    };
    auto stageB = [&](int dstart) {
        const int d = dstart + 4 * lane;
        const int e0 = 2 * (d - 384);
        if (e0 < NT) {
            const float4 v = *(const float4*)(g2 + e0);
            const float4 w = *(const float4*)(g2 + e0 + 4);
            int4 p;
            p.x = (int)(f2bf(v.x) | (f2bf(v.y) << 16));
            p.y = (int)(f2bf(v.z) | (f2bf(v.w) << 16));
            p.z = (int)(f2bf(w.x) | (f2bf(w.y) << 16));
            p.w = (int)(f2bf(w.z) | (f2bf(w.w) << 16));
            *(int4*)(l2 + d) = p;
        }
    };

    // --- Prologue: A dwords [152,664), B dwords [384,896).
    stageA(152); stageA(408);
    stageB(384); stageB(640);

    // --- B FIFO prefill: slot s <- tile0 frag of step s-16 (reads [16,512)).
    int4 fifo[16];
    {
        const int dbP = 256 + 4 * q - 16 * r;
        #pragma unroll
        for (int s = 0; s < 16; ++s)
            fifo[s] = *(const int4*)(l2 + dbP + 16 * s);
    }

    f32x4 a00 = {0.f,0.f,0.f,0.f};   // aPT: P = parity, T = n-tile
    f32x4 a10 = {0.f,0.f,0.f,0.f};
    f32x4 a01 = {0.f,0.f,0.f,0.f};
    f32x4 a11 = {0.f,0.f,0.f,0.f};

    int da = 130 + 4 * q + r;        // A dword base (+16/step)
    int db = 512 + 4 * q - 16 * r;   // tile0 B dword base (+16/step)
    int aPre = 664, bPre = 896;      // staged frontiers

    auto ldsFetch = [&](int daL, int dbL, AFrag& A, int4& B) {
        const uint* pa = (const uint*)l1 + daL;
        A.m1 = pa[-1]; A.d0 = pa[0]; A.d1 = pa[1]; A.d2 = pa[2]; A.d3 = pa[3];
        B = *(const int4*)((const uint*)l2 + dbL);
    };

    AFrag curA; int4 curB;
    ldsFetch(da, db, curA, curB);    // preload step 0
    AFrag nxtA = curA; int4 nxtB = curB;

    for (int c = 0; c < 6; ++c) {
        // Prefetch global loads for future chunks (issued before the MFMAs).
        const int dA = aPre + 4 * lane, eA = 2 * (dA - 152);
        const int dB = bPre + 4 * lane, eB = 2 * (dB - 384);
        const bool okA = eA < NT, okB = eB < NT;
        float4 va0, va1, vb0, vb1;
        if (okA) { va0 = *(const float4*)(g1 + eA); va1 = *(const float4*)(g1 + eA + 4); }
        if (okB) { vb0 = *(const float4*)(g2 + eB); vb1 = *(const float4*)(g2 + eB + 4); }

        #pragma unroll
        for (int u = 0; u < 16; ++u) {
            // Prefetch step u+1 (next chunk's step 0 at u=15; skip at the
            // very end: da/db for step 96 run past the LDS arrays).
            if (u < 15 || c < 5)
                ldsFetch(da + 16, db + 16, nxtA, nxtB);

            union { uint w[4]; bf16x8 v; int4 i4; } f1, f0, g0, g1u;
            f1.w[0] = curA.d0; f1.w[1] = curA.d1;                     // par=1
            f1.w[2] = curA.d2; f1.w[3] = curA.d3;
            f0.w[0] = (curA.m1 >> 16) | (curA.d0 << 16);              // par=0
            f0.w[1] = (curA.d0 >> 16) | (curA.d1 << 16);
            f0.w[2] = (curA.d1 >> 16) | (curA.d2 << 16);
            f0.w[3] = (curA.d2 >> 16) | (curA.d3 << 16);

            g0.i4  = curB;                   // tile0 (step i)
            g1u.i4 = fifo[u];                // tile1 (= tile0 @ i-16)
            fifo[u] = g0.i4;

            a00 = __builtin_amdgcn_mfma_f32_16x16x32_bf16(f0.v, g0.v,  a00, 0, 0, 0);
            a10 = __builtin_amdgcn_mfma_f32_16x16x32_bf16(f1.v, g0.v,  a10, 0, 0, 0);
            a01 = __builtin_amdgcn_mfma_f32_16x16x32_bf16(f0.v, g1u.v, a01, 0, 0, 0);
            a11 = __builtin_amdgcn_mfma_f32_16x16x32_bf16(f1.v, g1u.v, a11, 0, 0, 0);

            curA = nxtA; curB = nxtB;
            da += 16; db += 16;
        }

        // Convert + LDS write (read by chunk c+1/c+2 -> a chunk of slack).
        if (okA) {
            int4 p;
            p.x = (int)(f2bf(va0.x) | (f2bf(va0.y) << 16));
            p.y = (int)(f2bf(va0.z) | (f2bf(va0.w) << 16));
            p.z = (int)(f2bf(va1.x) | (f2bf(va1.y) << 16));
            p.w = (int)(f2bf(va1.z) | (f2bf(va1.w) << 16));
            *(int4*)(l1 + dA) = p;
        }
        if (okB) {
            int4 p;
            p.x = (int)(f2bf(vb0.x) | (f2bf(vb0.y) << 16));
            p.y = (int)(f2bf(vb0.z) | (f2bf(vb0.w) << 16));
            p.z = (int)(f2bf(vb1.x) | (f2bf(vb1.y) << 16));
            p.w = (int)(f2bf(vb1.z) | (f2bf(vb1.w) << 16));
            *(int4*)(l2 + dB) = p;
        }
        aPre += 256; bPre += 256;
    }

    // --- Store: lane (q,r), reg rr, parity p -> o = 512*tile + 32r + 8q + 2rr + p.
    float* o = out + (size_t)ch * NOUT;
    {
        const int X = 32 * r + 8 * q;            // tile0: X+7 <= 511 < 603
        float4 s0 = {a00[0], a10[0], a00[1], a10[1]};
        float4 s1 = {a00[2], a10[2], a00[3], a10[3]};
        *(float4*)(o + X)     = s0;
        *(float4*)(o + X + 4) = s1;
    }
    {
        const int X = 512 + 32 * r + 8 * q;
        if (X + 7 < NOUT) {
            float4 s0 = {a01[0], a11[0], a01[1], a11[1]};
            float4 s1 = {a01[2], a11[2], a01[3], a11[3]};
            *(float4*)(o + X)     = s0;
            *(float4*)(o + X + 4) = s1;
        } else if (X < NOUT) {
            const float v[8] = {a01[0], a11[0], a01[1], a11[1],
                                a01[2], a11[2], a01[3], a11[3]};
            #pragma unroll
            for (int e = 0; e < 8; ++e)
                if (X + e < NOUT) o[X + e] = v[e];
        }
    }
}

extern "C" void kernel_launch(void* const* d_in, const int* in_sizes, int n_in,
                              void* d_out, int out_size, void* d_ws, size_t ws_size,
                              hipStream_t stream) {
    const float* d1 = (const float*)d_in[0];
    const float* d2 = (const float*)d_in[1];
    float* out = (float*)d_out;
    const int nChannels = in_sizes[0] / NT;     // 2048
    xcorr_mfma<<<nChannels, BLOCK, 0, stream>>>(d1, d2, out);
}